// Round 13
// baseline (314.856 us; speedup 1.0000x reference)
//
#include <hip/hip_runtime.h>
#include <hip/hip_bf16.h>

typedef unsigned short u16;
typedef __bf16 bf16x8 __attribute__((ext_vector_type(8)));
typedef u16 u16x8 __attribute__((ext_vector_type(8)));
typedef float f32x4 __attribute__((ext_vector_type(4)));

__device__ __forceinline__ float bf2f(u16 u) {
  union { unsigned u32; float f; } c; c.u32 = ((unsigned)u) << 16; return c.f;
}
__device__ __forceinline__ u16 f2bf(float f) {
  union { float f; unsigned u32; } c; c.f = f;
  unsigned r = c.u32 + 0x7FFFu + ((c.u32 >> 16) & 1u);
  return (u16)(r >> 16);
}

#define GLD16(gp, lp) __builtin_amdgcn_global_load_lds( \
    (const __attribute__((address_space(1))) void*)(gp), \
    (__attribute__((address_space(3))) void*)(lp), 16, 0, 0)

// ---------------------------------------------------------------------------
// fused fp32 -> bf16 cast over three concatenated logical buffers.
// ---------------------------------------------------------------------------
__global__ __launch_bounds__(256)
void cast3_f32_bf16_kernel(const float* __restrict__ in0, u16* __restrict__ out0, int n0,
                           const float* __restrict__ in1, u16* __restrict__ out1, int n1,
                           const float* __restrict__ in2, u16* __restrict__ out2, int n2) {
  int i = (blockIdx.x * 256 + threadIdx.x) * 4;
  const float* in; u16* out;
  if (i < n0)            { in = in0; out = out0; }
  else if (i < n0 + n1)  { in = in1; out = out1; i -= n0; }
  else if (i < n0 + n1 + n2) { in = in2; out = out2; i -= n0 + n1; }
  else return;
  float4 v = *(const float4*)(in + i);
  ushort4 o;
  o.x = f2bf(v.x); o.y = f2bf(v.y); o.z = f2bf(v.z); o.w = f2bf(v.w);
  *(ushort4*)(out + i) = o;
}

// ===========================================================================
// 8-phase 256x256 GEMM, BK=32, LDS 64KB -> 2 blocks/CU (co-residency hides
// barrier latency; the 1-block BK=64 version was barrier-latency-bound at
// ~860cy/phase). Same validated schedule skeleton as rounds 9-12:
// regions: 0=A[0:128), 1=A[128:256), 2=B[0:128), 3=B[128:256); [128][32] each.
// Stage slots: ph2=B0(t+2), ph3=B1(t+2), ph4=A0+A1(t+2); mirrored ph6-8 for
// t+3 into dbuf1. Counted vmcnt: 4 loads/half-iter -> VMC4 at ph4/ph8 drains
// exactly the previous half's tile (audit: queue [prev4, this4] -> leaves 4).
// Swizzle: 64B rows, 4 slots of 16B; phys_slot = logical ^ (row&3).
// ds_read XOR (lane16&3)<<4; GLD16 source col ((l&3)^((l>>2)&3))*8 (inverse).
// Residual 4-way read conflict (unavoidable at 64B rows) ~ 1.6x LDS, hidden.
// Split epilogue: bn 0-2 -> qT[b][h][48][1024], 3-5 -> kT, 6-8 -> v n-major.
// ===========================================================================
__global__ __launch_bounds__(512, 2)
void gemm8p_qkv_kernel(const u16* __restrict__ A, const u16* __restrict__ B,
                       u16* __restrict__ qT, u16* __restrict__ kT,
                       u16* __restrict__ vb,
                       int K, int nbn, int niter) {
  __shared__ alignas(16) u16 lds[2][4][128][32];   // 65536 B
  const int tid = threadIdx.x;
  const int l = tid & 63, w = tid >> 6;
  const int lane16 = l & 15, lg = l >> 4;
  const int wm = w >> 2, wn = w & 3;
  const int rsub = l >> 2;                         // row within wave's 16
  const int colsw = (((l & 3) ^ (rsub & 3)) * 8);  // inverse-swizzled src col
  const int swzrd = (lane16 & 3) << 4;             // read-side XOR

  const int cpx = gridDim.x >> 3;
  const int swz = (blockIdx.x & 7) * cpx + (blockIdx.x >> 3);
  const int bm = swz / nbn, bn = swz - bm * nbn;

  const u16* rbase[4] = {
    A + (size_t)(bm * 256) * K,        A + (size_t)(bm * 256 + 128) * K,
    B + (size_t)(bn * 256) * K,        B + (size_t)(bn * 256 + 128) * K };

  const f32x4 zero = {0.f, 0.f, 0.f, 0.f};
  f32x4 acc[8][4];
#pragma unroll
  for (int i = 0; i < 8; ++i)
#pragma unroll
    for (int j = 0; j < 4; ++j) acc[i][j] = zero;

  bf16x8 af[4], bf[2][2];

#define STG(D, REG, T) \
  GLD16(rbase[REG] + (size_t)(w * 16 + rsub) * K + colsw + (T) * 32, \
        (char*)&lds[D][REG][0][0] + w * 1024)

#define RD_A(D, MH) do { \
  _Pragma("unroll") for (int m = 0; m < 4; ++m) \
    af[m] = *(const bf16x8*)((const char*)&lds[D][wm][0][0] \
        + ((MH) * 64 + m * 16 + lane16) * 64 + ((lg * 16) ^ swzrd)); \
  } while (0)

#define RD_B(D, NH) do { \
  _Pragma("unroll") for (int nh = 0; nh < 2; ++nh) \
  _Pragma("unroll") for (int n = 0; n < 2; ++n) \
    bf[nh][n] = *(const bf16x8*)((const char*)&lds[D][2 + (wn >> 1)][0][0] \
        + ((wn & 1) * 64 + (nh * 2 + n) * 16 + lane16) * 64 \
        + ((lg * 16) ^ swzrd)); \
  } while (0)

#define QUAD(MH, NH) do { \
  __builtin_amdgcn_s_setprio(1); \
  _Pragma("unroll") for (int m = 0; m < 4; ++m) \
  _Pragma("unroll") for (int n = 0; n < 2; ++n) \
    acc[(MH) * 4 + m][(NH) * 2 + n] = __builtin_amdgcn_mfma_f32_16x16x32_bf16( \
        af[m], bf[NH][n], acc[(MH) * 4 + m][(NH) * 2 + n], 0, 0, 0); \
  __builtin_amdgcn_s_setprio(0); \
  } while (0)

#define BARR  do { asm volatile("s_barrier" ::: "memory"); \
                   __builtin_amdgcn_sched_barrier(0); } while (0)
#define LGKM0 asm volatile("s_waitcnt lgkmcnt(0)" ::: "memory")
#define SB0   __builtin_amdgcn_sched_barrier(0)
#define VMC4  asm volatile("s_waitcnt vmcnt(4)" ::: "memory")
#define VMC0  asm volatile("s_waitcnt vmcnt(0)" ::: "memory")

  // prologue: tiles 0 (buf0) and 1 (buf1), 8 loads, full drain
#pragma unroll
  for (int reg = 0; reg < 4; ++reg) {
    STG(0, reg, 0);
    STG(1, reg, 1);
  }
  VMC0; BARR;

  for (int it = 0; it < niter; ++it) {
    const int t = 2 * it;
    const bool pf = (it < niter - 1);
    // ph1: (mh0,nh0) buf0; reads A(region wm) + B(regions 2,3)
    RD_A(0, 0); RD_B(0, 0);
    BARR; LGKM0; SB0; QUAD(0, 0); BARR;
    // ph2: stage t+2: B0 (region 2; B last read ph1)
    if (pf) { STG(0, 2, t + 2); }
    BARR; LGKM0; SB0; QUAD(0, 1); BARR;
    // ph3: reads A again; stage t+2: B1 (region 3)
    RD_A(0, 1);
    if (pf) { STG(0, 3, t + 2); }
    BARR; LGKM0; SB0; QUAD(1, 1); BARR;
    // ph4: stage t+2: A0+A1 (A last read ph3); counted vmcnt
    if (pf) { STG(0, 0, t + 2); STG(0, 1, t + 2); }
    BARR; LGKM0; SB0; QUAD(1, 0);
    if (pf) { VMC4; } else { VMC0; }
    BARR;
    // ph5: (mh0,nh0) buf1
    RD_A(1, 0); RD_B(1, 0);
    BARR; LGKM0; SB0; QUAD(0, 0); BARR;
    // ph6: stage t+3: B0'
    if (pf) { STG(1, 2, t + 3); }
    BARR; LGKM0; SB0; QUAD(0, 1); BARR;
    // ph7: stage t+3: B1'
    RD_A(1, 1);
    if (pf) { STG(1, 3, t + 3); }
    BARR; LGKM0; SB0; QUAD(1, 1); BARR;
    // ph8: stage t+3: A0'+A1'; counted vmcnt
    if (pf) { STG(1, 0, t + 3); STG(1, 1, t + 3); }
    BARR; LGKM0; SB0; QUAD(1, 0);
    if (pf) { VMC4; } else { VMC0; }
    BARR;
  }

#undef STG
#undef RD_A
#undef RD_B
#undef QUAD
#undef BARR
#undef LGKM0
#undef SB0
#undef VMC4
#undef VMC0

  // split epilogue: frag D layout col = lane16, row = lg*4 + r
  const int row00 = bm * 256 + wm * 128, col00 = bn * 256 + wn * 64;
  const int mode = bn / 3;            // 0=q, 1=k, 2=v (768 = 3*256 aligned)
  const int chbase = col00 - mode * 768;
  if (mode < 2) {
    u16* dstm = mode == 0 ? qT : kT;
    const int b = row00 >> 10;
    const int nbase = row00 & 1023;
#pragma unroll
    for (int nf = 0; nf < 4; ++nf) {
      const int ch = chbase + nf * 16 + lane16;       // 0..767
      const int h = (ch * 1366) >> 16;                // ch/48 (exact <768)
      const int d = ch - h * 48;
      u16* colp = dstm + (((size_t)b * 16 + h) * 48 + d) * 1024 + nbase;
#pragma unroll
      for (int mf = 0; mf < 8; ++mf) {
        const int n = mf * 16 + lg * 4;
        ushort4 pk;
        pk.x = f2bf(acc[mf][nf][0]); pk.y = f2bf(acc[mf][nf][1]);
        pk.z = f2bf(acc[mf][nf][2]); pk.w = f2bf(acc[mf][nf][3]);
        *(ushort4*)&colp[n] = pk;
      }
    }
  } else {
#pragma unroll
    for (int mf = 0; mf < 8; ++mf) {
#pragma unroll
      for (int nf = 0; nf < 4; ++nf) {
        const int ch = chbase + nf * 16 + lane16;
        const int rb = row00 + mf * 16 + lg * 4;
#pragma unroll
        for (int r = 0; r < 4; ++r)
          vb[(size_t)(rb + r) * 768 + ch] = f2bf(acc[mf][nf][r]);
      }
    }
  }
}

// ---------------------------------------------------------------------------
// BK=96 128x128 GEMM — projection GEMM (fp32 out + bias).
// ---------------------------------------------------------------------------
template<int BIAS, int OUTF32>
__global__ __launch_bounds__(256)
void gemm_bt_kernel(const u16* __restrict__ A, const u16* __restrict__ B,
                    void* __restrict__ Cv, const float* __restrict__ bias,
                    int M, int N, int K, int nbn) {
  __shared__ alignas(16) u16 As[3][128][32];
  __shared__ alignas(16) u16 Bs[3][128][32];
  const int tid = threadIdx.x;
  const int l = tid & 63, w = tid >> 6;
  const int lane16 = l & 15, lg = l >> 4;
  const int wr = w >> 1, wc = w & 1;
  const int cpx = gridDim.x >> 3;
  const int swz = (blockIdx.x & 7) * cpx + (blockIdx.x >> 3);
  const int bm = swz / nbn, bn = swz - bm * nbn;

  const f32x4 zero = {0.f, 0.f, 0.f, 0.f};
  f32x4 acc[4][4];
#pragma unroll
  for (int i = 0; i < 4; ++i)
#pragma unroll
    for (int j = 0; j < 4; ++j) acc[i][j] = zero;

  const int r0 = tid >> 2, e0 = (tid & 3) * 8;
  const u16* Ap0 = A + (size_t)(bm * 128 + r0) * K + e0;
  const u16* Ap1 = A + (size_t)(bm * 128 + r0 + 64) * K + e0;
  const u16* Bp0 = B + (size_t)(bn * 128 + r0) * K + e0;
  const u16* Bp1 = B + (size_t)(bn * 128 + r0 + 64) * K + e0;

  for (int k0 = 0; k0 < K; k0 += 96) {
#pragma unroll
    for (int kk = 0; kk < 3; ++kk) {
      const int ko = k0 + kk * 32;
      GLD16(Ap0 + ko, (char*)&As[kk][0][0] + w * 1024);
      GLD16(Ap1 + ko, (char*)&As[kk][0][0] + 4096 + w * 1024);
      GLD16(Bp0 + ko, (char*)&Bs[kk][0][0] + w * 1024);
      GLD16(Bp1 + ko, (char*)&Bs[kk][0][0] + 4096 + w * 1024);
    }
    __syncthreads();

#pragma unroll
    for (int kk = 0; kk < 3; ++kk) {
      bf16x8 af[4], bfr[4];
#pragma unroll
      for (int i = 0; i < 4; ++i)
        af[i] = *(const bf16x8*)&As[kk][wr * 64 + i * 16 + lane16][lg * 8];
#pragma unroll
      for (int j = 0; j < 4; ++j)
        bfr[j] = *(const bf16x8*)&Bs[kk][wc * 64 + j * 16 + lane16][lg * 8];
#pragma unroll
      for (int i = 0; i < 4; ++i)
#pragma unroll
        for (int j = 0; j < 4; ++j)
          acc[i][j] = __builtin_amdgcn_mfma_f32_16x16x32_bf16(af[i], bfr[j], acc[i][j], 0, 0, 0);
    }
    __syncthreads();
  }

  const int row0 = bm * 128 + wr * 64, col0 = bn * 128 + wc * 64;
#pragma unroll
  for (int i = 0; i < 4; ++i) {
#pragma unroll
    for (int j = 0; j < 4; ++j) {
      const int col = col0 + j * 16 + lane16;
      const float badd = BIAS ? bias[col] : 0.f;
      const int rbase = row0 + i * 16 + lg * 4;
#pragma unroll
      for (int r = 0; r < 4; ++r) {
        const float v = acc[i][j][r] + badd;
        if (OUTF32) ((float*)Cv)[(size_t)(rbase + r) * N + col] = v;
        else        ((u16*)Cv)[(size_t)(rbase + r) * N + col] = f2bf(v);
      }
    }
  }
}

// ---------------------------------------------------------------------------
// XCA attention core v3 (passing). One block (4 waves) per (b,h).
// ---------------------------------------------------------------------------
__global__ __launch_bounds__(256)
void xca_attn_kernel(const u16* __restrict__ qT, const u16* __restrict__ kT,
                     const u16* __restrict__ vb,
                     const float* __restrict__ temperature,
                     u16* __restrict__ aout) {
  const int tid = threadIdx.x;
  const int l = tid & 63, w = tid >> 6;
  const int lane16 = l & 15, lg = l >> 4;
  const int bh = blockIdx.x, b = bh >> 4, h = bh & 15;

  __shared__ alignas(16) float attn_raw[48][48];
  __shared__ alignas(16) u16 attn_bf[48][64];
  __shared__ float sqs[2][48];
  __shared__ float rn[2][48];

  for (int i = tid; i < 48 * 48; i += 256) ((float*)attn_raw)[i] = 0.f;
  if (tid < 96) ((float*)sqs)[tid] = 0.f;
  __syncthreads();

  const f32x4 zero = {0.f, 0.f, 0.f, 0.f};
  f32x4 pqk[3][3], pqq[3], pkk[3];
#pragma unroll
  for (int i = 0; i < 3; ++i) {
    pqq[i] = zero; pkk[i] = zero;
#pragma unroll
    for (int j = 0; j < 3; ++j) pqk[i][j] = zero;
  }

  const size_t hb = ((size_t)b * 16 + h) * 48 * 1024;
  const u16* qrow = qT + hb;
  const u16* krow = kT + hb;
  for (int s = 0; s < 8; ++s) {
    const int n0 = (s * 4 + w) * 32 + lg * 8;
    bf16x8 qf[3], kf[3];
#pragma unroll
    for (int i = 0; i < 3; ++i)
      qf[i] = *(const bf16x8*)&qrow[(i * 16 + lane16) * 1024 + n0];
#pragma unroll
    for (int j = 0; j < 3; ++j)
      kf[j] = *(const bf16x8*)&krow[(j * 16 + lane16) * 1024 + n0];
#pragma unroll
    for (int i = 0; i < 3; ++i)
#pragma unroll
      for (int j = 0; j < 3; ++j)
        pqk[i][j] = __builtin_amdgcn_mfma_f32_16x16x32_bf16(qf[i], kf[j], pqk[i][j], 0, 0, 0);
#pragma unroll
    for (int i = 0; i < 3; ++i) {
      pqq[i] = __builtin_amdgcn_mfma_f32_16x16x32_bf16(qf[i], qf[i], pqq[i], 0, 0, 0);
      pkk[i] = __builtin_amdgcn_mfma_f32_16x16x32_bf16(kf[i], kf[i], pkk[i], 0, 0, 0);
    }
  }

#pragma unroll
  for (int i = 0; i < 3; ++i)
#pragma unroll
    for (int j = 0; j < 3; ++j)
#pragma unroll
      for (int r = 0; r < 4; ++r)
        atomicAdd(&attn_raw[i * 16 + lg * 4 + r][j * 16 + lane16], pqk[i][j][r]);
  if (lg == (lane16 >> 2)) {
    const int r = lane16 & 3;
#pragma unroll
    for (int i = 0; i < 3; ++i) {
      atomicAdd(&sqs[0][i * 16 + lane16], pqq[i][r]);
      atomicAdd(&sqs[1][i * 16 + lane16], pkk[i][r]);
    }
  }
  __syncthreads();

  if (tid < 96) {
    const int m = tid / 48, d = tid % 48;
    rn[m][d] = 1.f / fmaxf(sqrtf(sqs[m][d]), 1e-12f);
  }
  __syncthreads();

  const float temp = temperature[h];
  if (tid < 48) {
    const float sr = rn[0][tid] * temp;
    float mx = -1e30f;
    for (int e = 0; e < 48; ++e)
      mx = fmaxf(mx, attn_raw[tid][e] * rn[1][e] * sr);
    float ssum = 0.f;
    for (int e = 0; e < 48; ++e) {
      const float p = __expf(attn_raw[tid][e] * rn[1][e] * sr - mx);
      attn_raw[tid][e] = p; ssum += p;
    }
    const float inv = 1.f / ssum;
    for (int e = 0; e < 48; ++e) attn_bf[tid][e] = f2bf(attn_raw[tid][e] * inv);
    for (int e = 48; e < 64; ++e) attn_bf[tid][e] = 0;
  }
  __syncthreads();

  bf16x8 af2[3][2];
#pragma unroll
  for (int i = 0; i < 3; ++i)
#pragma unroll
    for (int ks = 0; ks < 2; ++ks)
      af2[i][ks] = *(const bf16x8*)&attn_bf[i * 16 + lane16][ks * 32 + lg * 8];

  const bf16x8 zf = {0, 0, 0, 0, 0, 0, 0, 0};
  for (int nf = 0; nf < 16; ++nf) {
    const int n0 = w * 256 + nf * 16;
    const u16* vsrc = vb + (size_t)(b * 1024 + n0 + lane16) * 768 + h * 48 + lg * 8;
    bf16x8 vf0 = *(const bf16x8*)vsrc;
    bf16x8 vf1 = (lg < 2) ? *(const bf16x8*)(vsrc + 32) : zf;
#pragma unroll
    for (int i = 0; i < 3; ++i) {
      f32x4 acc = zero;
      acc = __builtin_amdgcn_mfma_f32_16x16x32_bf16(af2[i][0], vf0, acc, 0, 0, 0);
      acc = __builtin_amdgcn_mfma_f32_16x16x32_bf16(af2[i][1], vf1, acc, 0, 0, 0);
      const size_t oo = (size_t)(b * 1024 + n0 + lane16) * 768 + h * 48 + i * 16 + lg * 4;
      ushort4 pack;
      pack.x = f2bf(acc[0]); pack.y = f2bf(acc[1]);
      pack.z = f2bf(acc[2]); pack.w = f2bf(acc[3]);
      *(ushort4*)&aout[oo] = pack;
    }
  }
}

// ---------------------------------------------------------------------------
extern "C" void kernel_launch(void* const* d_in, const int* in_sizes, int n_in,
                              void* d_out, int out_size, void* d_ws, size_t ws_size,
                              hipStream_t stream) {
  const float* x      = (const float*)d_in[0];  // [32768][768]
  const float* w_qkv  = (const float*)d_in[1];  // [2304][768]
  const float* w_proj = (const float*)d_in[2];  // [768][768]
  const float* b_proj = (const float*)d_in[3];  // [768]
  const float* temp   = (const float*)d_in[4];  // [16]
  float* out = (float*)d_out;                   // [32768][768]

  u16* x_bf = (u16*)d_out;                                  // dead until GEMM2
  char* ws = (char*)d_ws;
  u16* qT        = (u16*)ws;                                // 50.33 MB [B][H][48][1024]
  u16* kT        = (u16*)(ws + (size_t)50331648);           // 50.33 MB
  u16* vbuf      = (u16*)(ws + (size_t)100663296);          // 50.33 MB [B*N][768]
  u16* aoutb     = (u16*)(ws + (size_t)150994944);          // 50.33 MB
  u16* w_qkv_bf  = (u16*)(ws + (size_t)201326592);          // 3.54 MB
  u16* w_proj_bf = (u16*)(ws + (size_t)204865536);          // 1.18 MB

  dim3 blk(256);
  const int n0 = 32768 * 768, n1 = 2304 * 768, n2 = 768 * 768;
  cast3_f32_bf16_kernel<<<dim3((n0 + n1 + n2) / 1024), blk, 0, stream>>>(
      x, x_bf, n0, w_qkv, w_qkv_bf, n1, w_proj, w_proj_bf, n2);

  // qkv GEMM (BK=32, 2 blocks/CU) -> qT, kT, v. grid 128x9 = 1152; 12 iters.
  gemm8p_qkv_kernel<<<dim3(1152), dim3(512), 0, stream>>>(
      x_bf, w_qkv_bf, qT, kT, vbuf, 768, 9, 12);
  // attention core -> aoutb [B,N,C] bf16
  xca_attn_kernel<<<dim3(512), blk, 0, stream>>>(qT, kT, vbuf, temp, aoutb);
  // out = aoutb @ w_proj^T + b_proj : BK=96 128^2, 256x6 -> 1536 blocks
  gemm_bt_kernel<1, 1><<<dim3(1536), blk, 0, stream>>>(
      aoutb, w_proj_bf, out, b_proj, 32768, 768, 768, 6);
}

// Round 14
// 303.478 us; speedup vs baseline: 1.0375x; 1.0375x over previous
//
#include <hip/hip_runtime.h>
#include <hip/hip_bf16.h>

typedef unsigned short u16;
typedef __bf16 bf16x8 __attribute__((ext_vector_type(8)));
typedef u16 u16x8 __attribute__((ext_vector_type(8)));
typedef float f32x4 __attribute__((ext_vector_type(4)));

__device__ __forceinline__ float bf2f(u16 u) {
  union { unsigned u32; float f; } c; c.u32 = ((unsigned)u) << 16; return c.f;
}
__device__ __forceinline__ u16 f2bf(float f) {
  union { float f; unsigned u32; } c; c.f = f;
  unsigned r = c.u32 + 0x7FFFu + ((c.u32 >> 16) & 1u);
  return (u16)(r >> 16);
}

#define GLD16(gp, lp) __builtin_amdgcn_global_load_lds( \
    (const __attribute__((address_space(1))) void*)(gp), \
    (__attribute__((address_space(3))) void*)(lp), 16, 0, 0)

// ---------------------------------------------------------------------------
// fused fp32 -> bf16 cast over three concatenated logical buffers.
// ---------------------------------------------------------------------------
__global__ __launch_bounds__(256)
void cast3_f32_bf16_kernel(const float* __restrict__ in0, u16* __restrict__ out0, int n0,
                           const float* __restrict__ in1, u16* __restrict__ out1, int n1,
                           const float* __restrict__ in2, u16* __restrict__ out2, int n2) {
  int i = (blockIdx.x * 256 + threadIdx.x) * 4;
  const float* in; u16* out;
  if (i < n0)            { in = in0; out = out0; }
  else if (i < n0 + n1)  { in = in1; out = out1; i -= n0; }
  else if (i < n0 + n1 + n2) { in = in2; out = out2; i -= n0 + n1; }
  else return;
  float4 v = *(const float4*)(in + i);
  ushort4 o;
  o.x = f2bf(v.x); o.y = f2bf(v.y); o.z = f2bf(v.z); o.w = f2bf(v.w);
  *(ushort4*)(out + i) = o;
}

// ===========================================================================
// 8-phase 256x256 GEMM, BK=64 (round-12 config, best verified: 155us, zero
// bank conflicts). Prologue micro-fix: VMC8 instead of VMC0 (wait tile 0
// only; tile 1's 8 loads stay in flight and are drained by ph4's VMC8,
// whose queue is [tile1 x8, t+2 x8] -> leaves exactly t+2's 8).
// Split epilogue: bn 0-2 -> qT[b][h][48][1024], 3-5 -> kT, 6-8 -> v n-major.
// ===========================================================================
__global__ __launch_bounds__(512, 2)
void gemm8p_qkv_kernel(const u16* __restrict__ A, const u16* __restrict__ B,
                       u16* __restrict__ qT, u16* __restrict__ kT,
                       u16* __restrict__ vb,
                       int K, int nbn, int niter) {
  __shared__ alignas(16) u16 lds[2][4][128][64];   // 131072 B
  const int tid = threadIdx.x;
  const int l = tid & 63, w = tid >> 6;
  const int lane16 = l & 15, lg = l >> 4;
  const int wm = w >> 2, wn = w & 3;
  const int lsub = l >> 3;
  const int colsw = ((l & 7) ^ lsub) * 8;      // inverse-swizzled source col
  const int swzrd = (lane16 & 7) << 4;         // read-side XOR

  const int cpx = gridDim.x >> 3;
  const int swz = (blockIdx.x & 7) * cpx + (blockIdx.x >> 3);
  const int bm = swz / nbn, bn = swz - bm * nbn;

  const u16* rbase[4] = {
    A + (size_t)(bm * 256) * K,        A + (size_t)(bm * 256 + 128) * K,
    B + (size_t)(bn * 256) * K,        B + (size_t)(bn * 256 + 128) * K };

  const f32x4 zero = {0.f, 0.f, 0.f, 0.f};
  f32x4 acc[8][4];
#pragma unroll
  for (int i = 0; i < 8; ++i)
#pragma unroll
    for (int j = 0; j < 4; ++j) acc[i][j] = zero;

  bf16x8 af[4][2], bf[2][2][2];

#define STG(D, REG, C, T) \
  GLD16(rbase[REG] + (size_t)((C) * 64 + w * 8 + lsub) * K + colsw + (T) * 64, \
        (char*)&lds[D][REG][0][0] + (C) * 8192 + w * 1024)

#define RD_A(D, MH) do { \
  _Pragma("unroll") for (int m = 0; m < 4; ++m) \
  _Pragma("unroll") for (int kh = 0; kh < 2; ++kh) \
    af[m][kh] = *(const bf16x8*)((const char*)&lds[D][wm][0][0] \
        + ((MH) * 64 + m * 16 + lane16) * 128 + ((kh * 64 + lg * 16) ^ swzrd)); \
  } while (0)

#define RD_B(D) do { \
  _Pragma("unroll") for (int nh = 0; nh < 2; ++nh) \
  _Pragma("unroll") for (int n = 0; n < 2; ++n) \
  _Pragma("unroll") for (int kh = 0; kh < 2; ++kh) \
    bf[nh][n][kh] = *(const bf16x8*)((const char*)&lds[D][2 + (wn >> 1)][0][0] \
        + ((wn & 1) * 64 + (nh * 2 + n) * 16 + lane16) * 128 \
        + ((kh * 64 + lg * 16) ^ swzrd)); \
  } while (0)

#define QUAD(MH, NH) do { \
  __builtin_amdgcn_s_setprio(1); \
  _Pragma("unroll") for (int m = 0; m < 4; ++m) \
  _Pragma("unroll") for (int n = 0; n < 2; ++n) \
  _Pragma("unroll") for (int kh = 0; kh < 2; ++kh) \
    acc[(MH) * 4 + m][(NH) * 2 + n] = __builtin_amdgcn_mfma_f32_16x16x32_bf16( \
        af[m][kh], bf[NH][n][kh], acc[(MH) * 4 + m][(NH) * 2 + n], 0, 0, 0); \
  __builtin_amdgcn_s_setprio(0); \
  } while (0)

#define BARR  do { asm volatile("s_barrier" ::: "memory"); \
                   __builtin_amdgcn_sched_barrier(0); } while (0)
#define LGKM0 asm volatile("s_waitcnt lgkmcnt(0)" ::: "memory")
#define SB0   __builtin_amdgcn_sched_barrier(0)
#define VMC8  asm volatile("s_waitcnt vmcnt(8)" ::: "memory")
#define VMC0  asm volatile("s_waitcnt vmcnt(0)" ::: "memory")

  // prologue: tiles 0 (buf0) and 1 (buf1); wait only tile 0 (tile 1's 8
  // loads stay in flight, drained by the first ph4 VMC8).
#pragma unroll
  for (int reg = 0; reg < 4; ++reg) { STG(0, reg, 0, 0); STG(0, reg, 1, 0); }
#pragma unroll
  for (int reg = 0; reg < 4; ++reg) { STG(1, reg, 0, 1); STG(1, reg, 1, 1); }
  VMC8; BARR;

  for (int it = 0; it < niter; ++it) {
    const int t = 2 * it;
    const bool pf = (it < niter - 1);
    // ph1: (mh0,nh0) buf0
    RD_A(0, 0); RD_B(0);
    BARR; LGKM0; SB0; QUAD(0, 0); BARR;
    // ph2: stage t+2: B0 (region 2; B last read ph1)
    if (pf) { STG(0, 2, 0, t + 2); STG(0, 2, 1, t + 2); }
    BARR; LGKM0; SB0; QUAD(0, 1); BARR;
    // ph3: reads A again; stage t+2: B1 (region 3)
    RD_A(0, 1);
    if (pf) { STG(0, 3, 0, t + 2); STG(0, 3, 1, t + 2); }
    BARR; LGKM0; SB0; QUAD(1, 1); BARR;
    // ph4: stage t+2: A0+A1 (A last read ph3); counted vmcnt
    if (pf) { STG(0, 0, 0, t + 2); STG(0, 0, 1, t + 2);
              STG(0, 1, 0, t + 2); STG(0, 1, 1, t + 2); }
    BARR; LGKM0; SB0; QUAD(1, 0);
    if (pf) { VMC8; } else { VMC0; }
    BARR;
    // ph5: (mh0,nh0) buf1
    RD_A(1, 0); RD_B(1);
    BARR; LGKM0; SB0; QUAD(0, 0); BARR;
    // ph6: stage t+3: B0'
    if (pf) { STG(1, 2, 0, t + 3); STG(1, 2, 1, t + 3); }
    BARR; LGKM0; SB0; QUAD(0, 1); BARR;
    // ph7: stage t+3: B1'
    RD_A(1, 1);
    if (pf) { STG(1, 3, 0, t + 3); STG(1, 3, 1, t + 3); }
    BARR; LGKM0; SB0; QUAD(1, 1); BARR;
    // ph8: stage t+3: A0'+A1'; counted vmcnt
    if (pf) { STG(1, 0, 0, t + 3); STG(1, 0, 1, t + 3);
              STG(1, 1, 0, t + 3); STG(1, 1, 1, t + 3); }
    BARR; LGKM0; SB0; QUAD(1, 0);
    if (pf) { VMC8; } else { VMC0; }
    BARR;
  }

#undef STG
#undef RD_A
#undef RD_B
#undef QUAD
#undef BARR
#undef LGKM0
#undef SB0
#undef VMC8
#undef VMC0

  // split epilogue: frag D layout col = lane16, row = lg*4 + r
  const int row00 = bm * 256 + wm * 128, col00 = bn * 256 + wn * 64;
  const int mode = bn / 3;            // 0=q, 1=k, 2=v (768 = 3*256 aligned)
  const int chbase = col00 - mode * 768;
  if (mode < 2) {
    u16* dstm = mode == 0 ? qT : kT;
    const int b = row00 >> 10;
    const int nbase = row00 & 1023;
#pragma unroll
    for (int nf = 0; nf < 4; ++nf) {
      const int ch = chbase + nf * 16 + lane16;       // 0..767
      const int h = (ch * 1366) >> 16;                // ch/48 (exact <768)
      const int d = ch - h * 48;
      u16* colp = dstm + (((size_t)b * 16 + h) * 48 + d) * 1024 + nbase;
#pragma unroll
      for (int mf = 0; mf < 8; ++mf) {
        const int n = mf * 16 + lg * 4;
        ushort4 pk;
        pk.x = f2bf(acc[mf][nf][0]); pk.y = f2bf(acc[mf][nf][1]);
        pk.z = f2bf(acc[mf][nf][2]); pk.w = f2bf(acc[mf][nf][3]);
        *(ushort4*)&colp[n] = pk;
      }
    }
  } else {
#pragma unroll
    for (int mf = 0; mf < 8; ++mf) {
#pragma unroll
      for (int nf = 0; nf < 4; ++nf) {
        const int ch = chbase + nf * 16 + lane16;
        const int rb = row00 + mf * 16 + lg * 4;
#pragma unroll
        for (int r = 0; r < 4; ++r)
          vb[(size_t)(rb + r) * 768 + ch] = f2bf(acc[mf][nf][r]);
      }
    }
  }
}

// ---------------------------------------------------------------------------
// BK=96 128x128 GEMM — projection GEMM (fp32 out + bias).
// ---------------------------------------------------------------------------
template<int BIAS, int OUTF32>
__global__ __launch_bounds__(256)
void gemm_bt_kernel(const u16* __restrict__ A, const u16* __restrict__ B,
                    void* __restrict__ Cv, const float* __restrict__ bias,
                    int M, int N, int K, int nbn) {
  __shared__ alignas(16) u16 As[3][128][32];
  __shared__ alignas(16) u16 Bs[3][128][32];
  const int tid = threadIdx.x;
  const int l = tid & 63, w = tid >> 6;
  const int lane16 = l & 15, lg = l >> 4;
  const int wr = w >> 1, wc = w & 1;
  const int cpx = gridDim.x >> 3;
  const int swz = (blockIdx.x & 7) * cpx + (blockIdx.x >> 3);
  const int bm = swz / nbn, bn = swz - bm * nbn;

  const f32x4 zero = {0.f, 0.f, 0.f, 0.f};
  f32x4 acc[4][4];
#pragma unroll
  for (int i = 0; i < 4; ++i)
#pragma unroll
    for (int j = 0; j < 4; ++j) acc[i][j] = zero;

  const int r0 = tid >> 2, e0 = (tid & 3) * 8;
  const u16* Ap0 = A + (size_t)(bm * 128 + r0) * K + e0;
  const u16* Ap1 = A + (size_t)(bm * 128 + r0 + 64) * K + e0;
  const u16* Bp0 = B + (size_t)(bn * 128 + r0) * K + e0;
  const u16* Bp1 = B + (size_t)(bn * 128 + r0 + 64) * K + e0;

  for (int k0 = 0; k0 < K; k0 += 96) {
#pragma unroll
    for (int kk = 0; kk < 3; ++kk) {
      const int ko = k0 + kk * 32;
      GLD16(Ap0 + ko, (char*)&As[kk][0][0] + w * 1024);
      GLD16(Ap1 + ko, (char*)&As[kk][0][0] + 4096 + w * 1024);
      GLD16(Bp0 + ko, (char*)&Bs[kk][0][0] + w * 1024);
      GLD16(Bp1 + ko, (char*)&Bs[kk][0][0] + 4096 + w * 1024);
    }
    __syncthreads();

#pragma unroll
    for (int kk = 0; kk < 3; ++kk) {
      bf16x8 af[4], bfr[4];
#pragma unroll
      for (int i = 0; i < 4; ++i)
        af[i] = *(const bf16x8*)&As[kk][wr * 64 + i * 16 + lane16][lg * 8];
#pragma unroll
      for (int j = 0; j < 4; ++j)
        bfr[j] = *(const bf16x8*)&Bs[kk][wc * 64 + j * 16 + lane16][lg * 8];
#pragma unroll
      for (int i = 0; i < 4; ++i)
#pragma unroll
        for (int j = 0; j < 4; ++j)
          acc[i][j] = __builtin_amdgcn_mfma_f32_16x16x32_bf16(af[i], bfr[j], acc[i][j], 0, 0, 0);
    }
    __syncthreads();
  }

  const int row0 = bm * 128 + wr * 64, col0 = bn * 128 + wc * 64;
#pragma unroll
  for (int i = 0; i < 4; ++i) {
#pragma unroll
    for (int j = 0; j < 4; ++j) {
      const int col = col0 + j * 16 + lane16;
      const float badd = BIAS ? bias[col] : 0.f;
      const int rbase = row0 + i * 16 + lg * 4;
#pragma unroll
      for (int r = 0; r < 4; ++r) {
        const float v = acc[i][j][r] + badd;
        if (OUTF32) ((float*)Cv)[(size_t)(rbase + r) * N + col] = v;
        else        ((u16*)Cv)[(size_t)(rbase + r) * N + col] = f2bf(v);
      }
    }
  }
}

// ---------------------------------------------------------------------------
// XCA attention core v3 (passing). One block (4 waves) per (b,h).
// ---------------------------------------------------------------------------
__global__ __launch_bounds__(256)
void xca_attn_kernel(const u16* __restrict__ qT, const u16* __restrict__ kT,
                     const u16* __restrict__ vb,
                     const float* __restrict__ temperature,
                     u16* __restrict__ aout) {
  const int tid = threadIdx.x;
  const int l = tid & 63, w = tid >> 6;
  const int lane16 = l & 15, lg = l >> 4;
  const int bh = blockIdx.x, b = bh >> 4, h = bh & 15;

  __shared__ alignas(16) float attn_raw[48][48];
  __shared__ alignas(16) u16 attn_bf[48][64];
  __shared__ float sqs[2][48];
  __shared__ float rn[2][48];

  for (int i = tid; i < 48 * 48; i += 256) ((float*)attn_raw)[i] = 0.f;
  if (tid < 96) ((float*)sqs)[tid] = 0.f;
  __syncthreads();

  const f32x4 zero = {0.f, 0.f, 0.f, 0.f};
  f32x4 pqk[3][3], pqq[3], pkk[3];
#pragma unroll
  for (int i = 0; i < 3; ++i) {
    pqq[i] = zero; pkk[i] = zero;
#pragma unroll
    for (int j = 0; j < 3; ++j) pqk[i][j] = zero;
  }

  const size_t hb = ((size_t)b * 16 + h) * 48 * 1024;
  const u16* qrow = qT + hb;
  const u16* krow = kT + hb;
  for (int s = 0; s < 8; ++s) {
    const int n0 = (s * 4 + w) * 32 + lg * 8;
    bf16x8 qf[3], kf[3];
#pragma unroll
    for (int i = 0; i < 3; ++i)
      qf[i] = *(const bf16x8*)&qrow[(i * 16 + lane16) * 1024 + n0];
#pragma unroll
    for (int j = 0; j < 3; ++j)
      kf[j] = *(const bf16x8*)&krow[(j * 16 + lane16) * 1024 + n0];
#pragma unroll
    for (int i = 0; i < 3; ++i)
#pragma unroll
      for (int j = 0; j < 3; ++j)
        pqk[i][j] = __builtin_amdgcn_mfma_f32_16x16x32_bf16(qf[i], kf[j], pqk[i][j], 0, 0, 0);
#pragma unroll
    for (int i = 0; i < 3; ++i) {
      pqq[i] = __builtin_amdgcn_mfma_f32_16x16x32_bf16(qf[i], qf[i], pqq[i], 0, 0, 0);
      pkk[i] = __builtin_amdgcn_mfma_f32_16x16x32_bf16(kf[i], kf[i], pkk[i], 0, 0, 0);
    }
  }

#pragma unroll
  for (int i = 0; i < 3; ++i)
#pragma unroll
    for (int j = 0; j < 3; ++j)
#pragma unroll
      for (int r = 0; r < 4; ++r)
        atomicAdd(&attn_raw[i * 16 + lg * 4 + r][j * 16 + lane16], pqk[i][j][r]);
  if (lg == (lane16 >> 2)) {
    const int r = lane16 & 3;
#pragma unroll
    for (int i = 0; i < 3; ++i) {
      atomicAdd(&sqs[0][i * 16 + lane16], pqq[i][r]);
      atomicAdd(&sqs[1][i * 16 + lane16], pkk[i][r]);
    }
  }
  __syncthreads();

  if (tid < 96) {
    const int m = tid / 48, d = tid % 48;
    rn[m][d] = 1.f / fmaxf(sqrtf(sqs[m][d]), 1e-12f);
  }
  __syncthreads();

  const float temp = temperature[h];
  if (tid < 48) {
    const float sr = rn[0][tid] * temp;
    float mx = -1e30f;
    for (int e = 0; e < 48; ++e)
      mx = fmaxf(mx, attn_raw[tid][e] * rn[1][e] * sr);
    float ssum = 0.f;
    for (int e = 0; e < 48; ++e) {
      const float p = __expf(attn_raw[tid][e] * rn[1][e] * sr - mx);
      attn_raw[tid][e] = p; ssum += p;
    }
    const float inv = 1.f / ssum;
    for (int e = 0; e < 48; ++e) attn_bf[tid][e] = f2bf(attn_raw[tid][e] * inv);
    for (int e = 48; e < 64; ++e) attn_bf[tid][e] = 0;
  }
  __syncthreads();

  bf16x8 af2[3][2];
#pragma unroll
  for (int i = 0; i < 3; ++i)
#pragma unroll
    for (int ks = 0; ks < 2; ++ks)
      af2[i][ks] = *(const bf16x8*)&attn_bf[i * 16 + lane16][ks * 32 + lg * 8];

  const bf16x8 zf = {0, 0, 0, 0, 0, 0, 0, 0};
  for (int nf = 0; nf < 16; ++nf) {
    const int n0 = w * 256 + nf * 16;
    const u16* vsrc = vb + (size_t)(b * 1024 + n0 + lane16) * 768 + h * 48 + lg * 8;
    bf16x8 vf0 = *(const bf16x8*)vsrc;
    bf16x8 vf1 = (lg < 2) ? *(const bf16x8*)(vsrc + 32) : zf;
#pragma unroll
    for (int i = 0; i < 3; ++i) {
      f32x4 acc = zero;
      acc = __builtin_amdgcn_mfma_f32_16x16x32_bf16(af2[i][0], vf0, acc, 0, 0, 0);
      acc = __builtin_amdgcn_mfma_f32_16x16x32_bf16(af2[i][1], vf1, acc, 0, 0, 0);
      const size_t oo = (size_t)(b * 1024 + n0 + lane16) * 768 + h * 48 + i * 16 + lg * 4;
      ushort4 pack;
      pack.x = f2bf(acc[0]); pack.y = f2bf(acc[1]);
      pack.z = f2bf(acc[2]); pack.w = f2bf(acc[3]);
      *(ushort4*)&aout[oo] = pack;
    }
  }
}

// ---------------------------------------------------------------------------
extern "C" void kernel_launch(void* const* d_in, const int* in_sizes, int n_in,
                              void* d_out, int out_size, void* d_ws, size_t ws_size,
                              hipStream_t stream) {
  const float* x      = (const float*)d_in[0];  // [32768][768]
  const float* w_qkv  = (const float*)d_in[1];  // [2304][768]
  const float* w_proj = (const float*)d_in[2];  // [768][768]
  const float* b_proj = (const float*)d_in[3];  // [768]
  const float* temp   = (const float*)d_in[4];  // [16]
  float* out = (float*)d_out;                   // [32768][768]

  u16* x_bf = (u16*)d_out;                                  // dead until GEMM2
  char* ws = (char*)d_ws;
  u16* qT        = (u16*)ws;                                // 50.33 MB [B][H][48][1024]
  u16* kT        = (u16*)(ws + (size_t)50331648);           // 50.33 MB
  u16* vbuf      = (u16*)(ws + (size_t)100663296);          // 50.33 MB [B*N][768]
  u16* aoutb     = (u16*)(ws + (size_t)150994944);          // 50.33 MB
  u16* w_qkv_bf  = (u16*)(ws + (size_t)201326592);          // 3.54 MB
  u16* w_proj_bf = (u16*)(ws + (size_t)204865536);          // 1.18 MB

  dim3 blk(256);
  const int n0 = 32768 * 768, n1 = 2304 * 768, n2 = 768 * 768;
  cast3_f32_bf16_kernel<<<dim3((n0 + n1 + n2) / 1024), blk, 0, stream>>>(
      x, x_bf, n0, w_qkv, w_qkv_bf, n1, w_proj, w_proj_bf, n2);

  // qkv GEMM (BK=64 8-phase) -> qT, kT, v. grid 128x9 = 1152; 6 iters.
  gemm8p_qkv_kernel<<<dim3(1152), dim3(512), 0, stream>>>(
      x_bf, w_qkv_bf, qT, kT, vbuf, 768, 9, 6);
  // attention core -> aoutb [B,N,C] bf16
  xca_attn_kernel<<<dim3(512), blk, 0, stream>>>(qT, kT, vbuf, temp, aoutb);
  // out = aoutb @ w_proj^T + b_proj : BK=96 128^2, 256x6 -> 1536 blocks
  gemm_bt_kernel<1, 1><<<dim3(1536), blk, 0, stream>>>(
      aoutb, w_proj_bf, out, b_proj, 32768, 768, 768, 6);
}

// Round 15
// 294.890 us; speedup vs baseline: 1.0677x; 1.0291x over previous
//
#include <hip/hip_runtime.h>
#include <hip/hip_bf16.h>

typedef unsigned short u16;
typedef __bf16 bf16x8 __attribute__((ext_vector_type(8)));
typedef u16 u16x8 __attribute__((ext_vector_type(8)));
typedef float f32x4 __attribute__((ext_vector_type(4)));

__device__ __forceinline__ float bf2f(u16 u) {
  union { unsigned u32; float f; } c; c.u32 = ((unsigned)u) << 16; return c.f;
}
__device__ __forceinline__ u16 f2bf(float f) {
  union { float f; unsigned u32; } c; c.f = f;
  unsigned r = c.u32 + 0x7FFFu + ((c.u32 >> 16) & 1u);
  return (u16)(r >> 16);
}

#define GLD16(gp, lp) __builtin_amdgcn_global_load_lds( \
    (const __attribute__((address_space(1))) void*)(gp), \
    (__attribute__((address_space(3))) void*)(lp), 16, 0, 0)

// ---------------------------------------------------------------------------
// fused fp32 -> bf16 cast over three concatenated logical buffers.
// ---------------------------------------------------------------------------
__global__ __launch_bounds__(256)
void cast3_f32_bf16_kernel(const float* __restrict__ in0, u16* __restrict__ out0, int n0,
                           const float* __restrict__ in1, u16* __restrict__ out1, int n1,
                           const float* __restrict__ in2, u16* __restrict__ out2, int n2) {
  int i = (blockIdx.x * 256 + threadIdx.x) * 4;
  const float* in; u16* out;
  if (i < n0)            { in = in0; out = out0; }
  else if (i < n0 + n1)  { in = in1; out = out1; i -= n0; }
  else if (i < n0 + n1 + n2) { in = in2; out = out2; i -= n0 + n1; }
  else return;
  float4 v = *(const float4*)(in + i);
  ushort4 o;
  o.x = f2bf(v.x); o.y = f2bf(v.y); o.z = f2bf(v.z); o.w = f2bf(v.w);
  *(ushort4*)(out + i) = o;
}

// ===========================================================================
// 8-phase 256x256 GEMM, BK=64 — SINGLE-barrier phases. Round-14 schedule
// with the redundant pre-QUAD barrier removed: phase = [reads/stages]
// LGKM0 SB0 QUAD [VMC] BARR. WAR proof: a stage of region R in phase k is
// issued only after BARR(k-1); every wave's last read of R (phase <= k-1)
// was lgkm-drained before that wave's closing barrier of its phase, which
// precedes BARR(k-1) or is it -> all reads complete before any stage.
// Intra-phase reads||stages touch disjoint regions (slot discipline
// unchanged). RAW: VMC8 + closing barrier (unchanged). 8 barriers/iter
// (was 16) -> attacks the measured ~860cy/phase barrier overhead.
// Split epilogue: bn 0-2 -> qT[b][h][48][1024], 3-5 -> kT, 6-8 -> v n-major.
// ===========================================================================
__global__ __launch_bounds__(512, 2)
void gemm8p_qkv_kernel(const u16* __restrict__ A, const u16* __restrict__ B,
                       u16* __restrict__ qT, u16* __restrict__ kT,
                       u16* __restrict__ vb,
                       int K, int nbn, int niter) {
  __shared__ alignas(16) u16 lds[2][4][128][64];   // 131072 B
  const int tid = threadIdx.x;
  const int l = tid & 63, w = tid >> 6;
  const int lane16 = l & 15, lg = l >> 4;
  const int wm = w >> 2, wn = w & 3;
  const int lsub = l >> 3;
  const int colsw = ((l & 7) ^ lsub) * 8;      // inverse-swizzled source col
  const int swzrd = (lane16 & 7) << 4;         // read-side XOR

  const int cpx = gridDim.x >> 3;
  const int swz = (blockIdx.x & 7) * cpx + (blockIdx.x >> 3);
  const int bm = swz / nbn, bn = swz - bm * nbn;

  const u16* rbase[4] = {
    A + (size_t)(bm * 256) * K,        A + (size_t)(bm * 256 + 128) * K,
    B + (size_t)(bn * 256) * K,        B + (size_t)(bn * 256 + 128) * K };

  const f32x4 zero = {0.f, 0.f, 0.f, 0.f};
  f32x4 acc[8][4];
#pragma unroll
  for (int i = 0; i < 8; ++i)
#pragma unroll
    for (int j = 0; j < 4; ++j) acc[i][j] = zero;

  bf16x8 af[4][2], bf[2][2][2];

#define STG(D, REG, C, T) \
  GLD16(rbase[REG] + (size_t)((C) * 64 + w * 8 + lsub) * K + colsw + (T) * 64, \
        (char*)&lds[D][REG][0][0] + (C) * 8192 + w * 1024)

#define RD_A(D, MH) do { \
  _Pragma("unroll") for (int m = 0; m < 4; ++m) \
  _Pragma("unroll") for (int kh = 0; kh < 2; ++kh) \
    af[m][kh] = *(const bf16x8*)((const char*)&lds[D][wm][0][0] \
        + ((MH) * 64 + m * 16 + lane16) * 128 + ((kh * 64 + lg * 16) ^ swzrd)); \
  } while (0)

#define RD_B(D) do { \
  _Pragma("unroll") for (int nh = 0; nh < 2; ++nh) \
  _Pragma("unroll") for (int n = 0; n < 2; ++n) \
  _Pragma("unroll") for (int kh = 0; kh < 2; ++kh) \
    bf[nh][n][kh] = *(const bf16x8*)((const char*)&lds[D][2 + (wn >> 1)][0][0] \
        + ((wn & 1) * 64 + (nh * 2 + n) * 16 + lane16) * 128 \
        + ((kh * 64 + lg * 16) ^ swzrd)); \
  } while (0)

#define QUAD(MH, NH) do { \
  __builtin_amdgcn_s_setprio(1); \
  _Pragma("unroll") for (int m = 0; m < 4; ++m) \
  _Pragma("unroll") for (int n = 0; n < 2; ++n) \
  _Pragma("unroll") for (int kh = 0; kh < 2; ++kh) \
    acc[(MH) * 4 + m][(NH) * 2 + n] = __builtin_amdgcn_mfma_f32_16x16x32_bf16( \
        af[m][kh], bf[NH][n][kh], acc[(MH) * 4 + m][(NH) * 2 + n], 0, 0, 0); \
  __builtin_amdgcn_s_setprio(0); \
  } while (0)

#define BARR  do { asm volatile("s_barrier" ::: "memory"); \
                   __builtin_amdgcn_sched_barrier(0); } while (0)
#define LGKM0 asm volatile("s_waitcnt lgkmcnt(0)" ::: "memory")
#define SB0   __builtin_amdgcn_sched_barrier(0)
#define VMC8  asm volatile("s_waitcnt vmcnt(8)" ::: "memory")
#define VMC0  asm volatile("s_waitcnt vmcnt(0)" ::: "memory")

  // prologue: tiles 0 (buf0) and 1 (buf1); wait only tile 0 (tile 1's 8
  // loads drain at the first ph4 VMC8).
#pragma unroll
  for (int reg = 0; reg < 4; ++reg) { STG(0, reg, 0, 0); STG(0, reg, 1, 0); }
#pragma unroll
  for (int reg = 0; reg < 4; ++reg) { STG(1, reg, 0, 1); STG(1, reg, 1, 1); }
  VMC8; BARR;

  for (int it = 0; it < niter; ++it) {
    const int t = 2 * it;
    const bool pf = (it < niter - 1);
    // ph1: (mh0,nh0) buf0 — reads all buf0 regions
    RD_A(0, 0); RD_B(0);
    LGKM0; SB0; QUAD(0, 0); BARR;
    // ph2: stage t+2: B0 (region 2; last read ph1)
    if (pf) { STG(0, 2, 0, t + 2); STG(0, 2, 1, t + 2); }
    LGKM0; SB0; QUAD(0, 1); BARR;
    // ph3: reads A again; stage t+2: B1 (region 3; last read ph1)
    RD_A(0, 1);
    if (pf) { STG(0, 3, 0, t + 2); STG(0, 3, 1, t + 2); }
    LGKM0; SB0; QUAD(1, 1); BARR;
    // ph4: stage t+2: A0+A1 (regions 0,1; last read ph3); counted vmcnt
    if (pf) { STG(0, 0, 0, t + 2); STG(0, 0, 1, t + 2);
              STG(0, 1, 0, t + 2); STG(0, 1, 1, t + 2); }
    LGKM0; SB0; QUAD(1, 0);
    if (pf) { VMC8; } else { VMC0; }
    BARR;
    // ph5: (mh0,nh0) buf1
    RD_A(1, 0); RD_B(1);
    LGKM0; SB0; QUAD(0, 0); BARR;
    // ph6: stage t+3: B0'
    if (pf) { STG(1, 2, 0, t + 3); STG(1, 2, 1, t + 3); }
    LGKM0; SB0; QUAD(0, 1); BARR;
    // ph7: stage t+3: B1'
    RD_A(1, 1);
    if (pf) { STG(1, 3, 0, t + 3); STG(1, 3, 1, t + 3); }
    LGKM0; SB0; QUAD(1, 1); BARR;
    // ph8: stage t+3: A0'+A1'; counted vmcnt
    if (pf) { STG(1, 0, 0, t + 3); STG(1, 0, 1, t + 3);
              STG(1, 1, 0, t + 3); STG(1, 1, 1, t + 3); }
    LGKM0; SB0; QUAD(1, 0);
    if (pf) { VMC8; } else { VMC0; }
    BARR;
  }

#undef STG
#undef RD_A
#undef RD_B
#undef QUAD
#undef BARR
#undef LGKM0
#undef SB0
#undef VMC8
#undef VMC0

  // split epilogue: frag D layout col = lane16, row = lg*4 + r
  const int row00 = bm * 256 + wm * 128, col00 = bn * 256 + wn * 64;
  const int mode = bn / 3;            // 0=q, 1=k, 2=v (768 = 3*256 aligned)
  const int chbase = col00 - mode * 768;
  if (mode < 2) {
    u16* dstm = mode == 0 ? qT : kT;
    const int b = row00 >> 10;
    const int nbase = row00 & 1023;
#pragma unroll
    for (int nf = 0; nf < 4; ++nf) {
      const int ch = chbase + nf * 16 + lane16;       // 0..767
      const int h = (ch * 1366) >> 16;                // ch/48 (exact <768)
      const int d = ch - h * 48;
      u16* colp = dstm + (((size_t)b * 16 + h) * 48 + d) * 1024 + nbase;
#pragma unroll
      for (int mf = 0; mf < 8; ++mf) {
        const int n = mf * 16 + lg * 4;
        ushort4 pk;
        pk.x = f2bf(acc[mf][nf][0]); pk.y = f2bf(acc[mf][nf][1]);
        pk.z = f2bf(acc[mf][nf][2]); pk.w = f2bf(acc[mf][nf][3]);
        *(ushort4*)&colp[n] = pk;
      }
    }
  } else {
#pragma unroll
    for (int mf = 0; mf < 8; ++mf) {
#pragma unroll
      for (int nf = 0; nf < 4; ++nf) {
        const int ch = chbase + nf * 16 + lane16;
        const int rb = row00 + mf * 16 + lg * 4;
#pragma unroll
        for (int r = 0; r < 4; ++r)
          vb[(size_t)(rb + r) * 768 + ch] = f2bf(acc[mf][nf][r]);
      }
    }
  }
}

// ---------------------------------------------------------------------------
// BK=96 128x128 GEMM — projection GEMM (fp32 out + bias).
// ---------------------------------------------------------------------------
template<int BIAS, int OUTF32>
__global__ __launch_bounds__(256)
void gemm_bt_kernel(const u16* __restrict__ A, const u16* __restrict__ B,
                    void* __restrict__ Cv, const float* __restrict__ bias,
                    int M, int N, int K, int nbn) {
  __shared__ alignas(16) u16 As[3][128][32];
  __shared__ alignas(16) u16 Bs[3][128][32];
  const int tid = threadIdx.x;
  const int l = tid & 63, w = tid >> 6;
  const int lane16 = l & 15, lg = l >> 4;
  const int wr = w >> 1, wc = w & 1;
  const int cpx = gridDim.x >> 3;
  const int swz = (blockIdx.x & 7) * cpx + (blockIdx.x >> 3);
  const int bm = swz / nbn, bn = swz - bm * nbn;

  const f32x4 zero = {0.f, 0.f, 0.f, 0.f};
  f32x4 acc[4][4];
#pragma unroll
  for (int i = 0; i < 4; ++i)
#pragma unroll
    for (int j = 0; j < 4; ++j) acc[i][j] = zero;

  const int r0 = tid >> 2, e0 = (tid & 3) * 8;
  const u16* Ap0 = A + (size_t)(bm * 128 + r0) * K + e0;
  const u16* Ap1 = A + (size_t)(bm * 128 + r0 + 64) * K + e0;
  const u16* Bp0 = B + (size_t)(bn * 128 + r0) * K + e0;
  const u16* Bp1 = B + (size_t)(bn * 128 + r0 + 64) * K + e0;

  for (int k0 = 0; k0 < K; k0 += 96) {
#pragma unroll
    for (int kk = 0; kk < 3; ++kk) {
      const int ko = k0 + kk * 32;
      GLD16(Ap0 + ko, (char*)&As[kk][0][0] + w * 1024);
      GLD16(Ap1 + ko, (char*)&As[kk][0][0] + 4096 + w * 1024);
      GLD16(Bp0 + ko, (char*)&Bs[kk][0][0] + w * 1024);
      GLD16(Bp1 + ko, (char*)&Bs[kk][0][0] + 4096 + w * 1024);
    }
    __syncthreads();

#pragma unroll
    for (int kk = 0; kk < 3; ++kk) {
      bf16x8 af[4], bfr[4];
#pragma unroll
      for (int i = 0; i < 4; ++i)
        af[i] = *(const bf16x8*)&As[kk][wr * 64 + i * 16 + lane16][lg * 8];
#pragma unroll
      for (int j = 0; j < 4; ++j)
        bfr[j] = *(const bf16x8*)&Bs[kk][wc * 64 + j * 16 + lane16][lg * 8];
#pragma unroll
      for (int i = 0; i < 4; ++i)
#pragma unroll
        for (int j = 0; j < 4; ++j)
          acc[i][j] = __builtin_amdgcn_mfma_f32_16x16x32_bf16(af[i], bfr[j], acc[i][j], 0, 0, 0);
    }
    __syncthreads();
  }

  const int row0 = bm * 128 + wr * 64, col0 = bn * 128 + wc * 64;
#pragma unroll
  for (int i = 0; i < 4; ++i) {
#pragma unroll
    for (int j = 0; j < 4; ++j) {
      const int col = col0 + j * 16 + lane16;
      const float badd = BIAS ? bias[col] : 0.f;
      const int rbase = row0 + i * 16 + lg * 4;
#pragma unroll
      for (int r = 0; r < 4; ++r) {
        const float v = acc[i][j][r] + badd;
        if (OUTF32) ((float*)Cv)[(size_t)(rbase + r) * N + col] = v;
        else        ((u16*)Cv)[(size_t)(rbase + r) * N + col] = f2bf(v);
      }
    }
  }
}

// ---------------------------------------------------------------------------
// XCA attention core v3 (passing). One block (4 waves) per (b,h).
// ---------------------------------------------------------------------------
__global__ __launch_bounds__(256)
void xca_attn_kernel(const u16* __restrict__ qT, const u16* __restrict__ kT,
                     const u16* __restrict__ vb,
                     const float* __restrict__ temperature,
                     u16* __restrict__ aout) {
  const int tid = threadIdx.x;
  const int l = tid & 63, w = tid >> 6;
  const int lane16 = l & 15, lg = l >> 4;
  const int bh = blockIdx.x, b = bh >> 4, h = bh & 15;

  __shared__ alignas(16) float attn_raw[48][48];
  __shared__ alignas(16) u16 attn_bf[48][64];
  __shared__ float sqs[2][48];
  __shared__ float rn[2][48];

  for (int i = tid; i < 48 * 48; i += 256) ((float*)attn_raw)[i] = 0.f;
  if (tid < 96) ((float*)sqs)[tid] = 0.f;
  __syncthreads();

  const f32x4 zero = {0.f, 0.f, 0.f, 0.f};
  f32x4 pqk[3][3], pqq[3], pkk[3];
#pragma unroll
  for (int i = 0; i < 3; ++i) {
    pqq[i] = zero; pkk[i] = zero;
#pragma unroll
    for (int j = 0; j < 3; ++j) pqk[i][j] = zero;
  }

  const size_t hb = ((size_t)b * 16 + h) * 48 * 1024;
  const u16* qrow = qT + hb;
  const u16* krow = kT + hb;
  for (int s = 0; s < 8; ++s) {
    const int n0 = (s * 4 + w) * 32 + lg * 8;
    bf16x8 qf[3], kf[3];
#pragma unroll
    for (int i = 0; i < 3; ++i)
      qf[i] = *(const bf16x8*)&qrow[(i * 16 + lane16) * 1024 + n0];
#pragma unroll
    for (int j = 0; j < 3; ++j)
      kf[j] = *(const bf16x8*)&krow[(j * 16 + lane16) * 1024 + n0];
#pragma unroll
    for (int i = 0; i < 3; ++i)
#pragma unroll
      for (int j = 0; j < 3; ++j)
        pqk[i][j] = __builtin_amdgcn_mfma_f32_16x16x32_bf16(qf[i], kf[j], pqk[i][j], 0, 0, 0);
#pragma unroll
    for (int i = 0; i < 3; ++i) {
      pqq[i] = __builtin_amdgcn_mfma_f32_16x16x32_bf16(qf[i], qf[i], pqq[i], 0, 0, 0);
      pkk[i] = __builtin_amdgcn_mfma_f32_16x16x32_bf16(kf[i], kf[i], pkk[i], 0, 0, 0);
    }
  }

#pragma unroll
  for (int i = 0; i < 3; ++i)
#pragma unroll
    for (int j = 0; j < 3; ++j)
#pragma unroll
      for (int r = 0; r < 4; ++r)
        atomicAdd(&attn_raw[i * 16 + lg * 4 + r][j * 16 + lane16], pqk[i][j][r]);
  if (lg == (lane16 >> 2)) {
    const int r = lane16 & 3;
#pragma unroll
    for (int i = 0; i < 3; ++i) {
      atomicAdd(&sqs[0][i * 16 + lane16], pqq[i][r]);
      atomicAdd(&sqs[1][i * 16 + lane16], pkk[i][r]);
    }
  }
  __syncthreads();

  if (tid < 96) {
    const int m = tid / 48, d = tid % 48;
    rn[m][d] = 1.f / fmaxf(sqrtf(sqs[m][d]), 1e-12f);
  }
  __syncthreads();

  const float temp = temperature[h];
  if (tid < 48) {
    const float sr = rn[0][tid] * temp;
    float mx = -1e30f;
    for (int e = 0; e < 48; ++e)
      mx = fmaxf(mx, attn_raw[tid][e] * rn[1][e] * sr);
    float ssum = 0.f;
    for (int e = 0; e < 48; ++e) {
      const float p = __expf(attn_raw[tid][e] * rn[1][e] * sr - mx);
      attn_raw[tid][e] = p; ssum += p;
    }
    const float inv = 1.f / ssum;
    for (int e = 0; e < 48; ++e) attn_bf[tid][e] = f2bf(attn_raw[tid][e] * inv);
    for (int e = 48; e < 64; ++e) attn_bf[tid][e] = 0;
  }
  __syncthreads();

  bf16x8 af2[3][2];
#pragma unroll
  for (int i = 0; i < 3; ++i)
#pragma unroll
    for (int ks = 0; ks < 2; ++ks)
      af2[i][ks] = *(const bf16x8*)&attn_bf[i * 16 + lane16][ks * 32 + lg * 8];

  const bf16x8 zf = {0, 0, 0, 0, 0, 0, 0, 0};
  for (int nf = 0; nf < 16; ++nf) {
    const int n0 = w * 256 + nf * 16;
    const u16* vsrc = vb + (size_t)(b * 1024 + n0 + lane16) * 768 + h * 48 + lg * 8;
    bf16x8 vf0 = *(const bf16x8*)vsrc;
    bf16x8 vf1 = (lg < 2) ? *(const bf16x8*)(vsrc + 32) : zf;
#pragma unroll
    for (int i = 0; i < 3; ++i) {
      f32x4 acc = zero;
      acc = __builtin_amdgcn_mfma_f32_16x16x32_bf16(af2[i][0], vf0, acc, 0, 0, 0);
      acc = __builtin_amdgcn_mfma_f32_16x16x32_bf16(af2[i][1], vf1, acc, 0, 0, 0);
      const size_t oo = (size_t)(b * 1024 + n0 + lane16) * 768 + h * 48 + i * 16 + lg * 4;
      ushort4 pack;
      pack.x = f2bf(acc[0]); pack.y = f2bf(acc[1]);
      pack.z = f2bf(acc[2]); pack.w = f2bf(acc[3]);
      *(ushort4*)&aout[oo] = pack;
    }
  }
}

// ---------------------------------------------------------------------------
extern "C" void kernel_launch(void* const* d_in, const int* in_sizes, int n_in,
                              void* d_out, int out_size, void* d_ws, size_t ws_size,
                              hipStream_t stream) {
  const float* x      = (const float*)d_in[0];  // [32768][768]
  const float* w_qkv  = (const float*)d_in[1];  // [2304][768]
  const float* w_proj = (const float*)d_in[2];  // [768][768]
  const float* b_proj = (const float*)d_in[3];  // [768]
  const float* temp   = (const float*)d_in[4];  // [16]
  float* out = (float*)d_out;                   // [32768][768]

  u16* x_bf = (u16*)d_out;                                  // dead until GEMM2
  char* ws = (char*)d_ws;
  u16* qT        = (u16*)ws;                                // 50.33 MB [B][H][48][1024]
  u16* kT        = (u16*)(ws + (size_t)50331648);           // 50.33 MB
  u16* vbuf      = (u16*)(ws + (size_t)100663296);          // 50.33 MB [B*N][768]
  u16* aoutb     = (u16*)(ws + (size_t)150994944);          // 50.33 MB
  u16* w_qkv_bf  = (u16*)(ws + (size_t)201326592);          // 3.54 MB
  u16* w_proj_bf = (u16*)(ws + (size_t)204865536);          // 1.18 MB

  dim3 blk(256);
  const int n0 = 32768 * 768, n1 = 2304 * 768, n2 = 768 * 768;
  cast3_f32_bf16_kernel<<<dim3((n0 + n1 + n2) / 1024), blk, 0, stream>>>(
      x, x_bf, n0, w_qkv, w_qkv_bf, n1, w_proj, w_proj_bf, n2);

  // qkv GEMM (BK=64 8-phase, single-barrier phases) -> qT, kT, v.
  gemm8p_qkv_kernel<<<dim3(1152), dim3(512), 0, stream>>>(
      x_bf, w_qkv_bf, qT, kT, vbuf, 768, 9, 6);
  // attention core -> aoutb [B,N,C] bf16
  xca_attn_kernel<<<dim3(512), blk, 0, stream>>>(qT, kT, vbuf, temp, aoutb);
  // out = aoutb @ w_proj^T + b_proj : BK=96 128^2, 256x6 -> 1536 blocks
  gemm_bt_kernel<1, 1><<<dim3(1536), blk, 0, stream>>>(
      aoutb, w_proj_bf, out, b_proj, 32768, 768, 768, 6);
}